// Round 1
// baseline (1291.710 us; speedup 1.0000x reference)
//
#include <hip/hip_runtime.h>

#define IN_DIM   128
#define HIDDEN   512
#define NCLASS   10
#define TSTEPS   512
#define BATCH    512
#define BETA     0.9f
#define THRESH   0.15f

// One block per batch element b (512 blocks), one thread per hidden unit h
// (512 threads = 8 waves). Each thread:
//   - holds its W1 row (128 floats) in registers for all 512 timesteps
//   - x[b,t,:] is wave-uniform -> compiler can use scalar loads (broadcast)
//   - runs the LIF recurrence in registers
//   - accumulates a SPIKE COUNT only: acc = W2 . spike_counts (exact algebra,
//     since acc contribution of h is (#spikes_h) * W2[c,h])
__global__ __launch_bounds__(HIDDEN, 2) void snn_fused(
    const float* __restrict__ x,    // [B, T, D]
    const float* __restrict__ W1,   // [H, D]
    const float* __restrict__ b1,   // [H]
    const float* __restrict__ W2,   // [C, H]
    const float* __restrict__ b2,   // [C]
    float* __restrict__ out)        // [B, C]
{
    const int b = blockIdx.x;
    const int h = threadIdx.x;

    // ---- Load W1 row into registers (fully unrolled, constant indices) ----
    float w1r[IN_DIM];
    const float4* w1v = reinterpret_cast<const float4*>(W1 + (size_t)h * IN_DIM);
#pragma unroll
    for (int i = 0; i < IN_DIM / 4; ++i) {
        float4 v = w1v[i];
        w1r[4 * i + 0] = v.x;
        w1r[4 * i + 1] = v.y;
        w1r[4 * i + 2] = v.z;
        w1r[4 * i + 3] = v.w;
    }
    const float b1h = b1[h];

    float mem = 0.0f;
    float cnt = 0.0f;

    const float4* xrow = reinterpret_cast<const float4*>(x + (size_t)b * TSTEPS * IN_DIM);

    for (int t = 0; t < TSTEPS; ++t) {
        const float4* xt = xrow + t * (IN_DIM / 4);
        // 4 independent FMA chains to hide VALU latency
        float d0 = 0.0f, d1 = 0.0f, d2 = 0.0f, d3 = 0.0f;
#pragma unroll
        for (int i = 0; i < IN_DIM / 4; ++i) {
            float4 v = xt[i];
            d0 = fmaf(v.x, w1r[4 * i + 0], d0);
            d1 = fmaf(v.y, w1r[4 * i + 1], d1);
            d2 = fmaf(v.z, w1r[4 * i + 2], d2);
            d3 = fmaf(v.w, w1r[4 * i + 3], d3);
        }
        float dot = (d0 + d1) + (d2 + d3);
        float cur = fmaf(2.0f, dot, b1h);           // xs = 2*x folded in here
        float dec = fmaf(BETA, mem, cur);           // beta*mem + cur
        // reset uses PREVIOUS mem (snntorch order)
        mem = (mem > THRESH) ? (dec - THRESH) : dec;
        cnt += (mem > THRESH) ? 1.0f : 0.0f;        // spike counter
    }

    // ---- Reduce: out[b,c] = (sum_h cnt_h * W2[c,h]) / T + b2[c] ----
    __shared__ float wred[8][NCLASS];
    const int lane = h & 63;
    const int wave = h >> 6;
#pragma unroll
    for (int c = 0; c < NCLASS; ++c) {
        float v = cnt * W2[c * HIDDEN + h];
#pragma unroll
        for (int off = 32; off >= 1; off >>= 1)
            v += __shfl_xor(v, off, 64);
        if (lane == 0) wred[wave][c] = v;
    }
    __syncthreads();
    if (h < NCLASS) {
        float s = 0.0f;
#pragma unroll
        for (int w = 0; w < 8; ++w) s += wred[w][h];
        out[(size_t)b * NCLASS + h] = s * (1.0f / (float)TSTEPS) + b2[h];
    }
}

extern "C" void kernel_launch(void* const* d_in, const int* in_sizes, int n_in,
                              void* d_out, int out_size, void* d_ws, size_t ws_size,
                              hipStream_t stream) {
    const float* x  = (const float*)d_in[0];
    const float* W1 = (const float*)d_in[1];
    const float* b1 = (const float*)d_in[2];
    const float* W2 = (const float*)d_in[3];
    const float* b2 = (const float*)d_in[4];
    float* out = (float*)d_out;

    snn_fused<<<dim3(BATCH), dim3(HIDDEN), 0, stream>>>(x, W1, b1, W2, b2, out);
}

// Round 2
// 224.628 us; speedup vs baseline: 5.7505x; 5.7505x over previous
//
#include <hip/hip_runtime.h>

#define IN_DIM  128
#define HIDDEN  512
#define NCLASS  10
#define TSTEPS  512
#define BATCH   512
#define BETA    0.9f
#define THRESH  0.15f

typedef __attribute__((ext_vector_type(8))) short bf16x8;
typedef __attribute__((ext_vector_type(4))) float f32x4;

__device__ __forceinline__ unsigned short f2bf_rne(float f) {
    unsigned int u = __float_as_uint(f);
    u += 0x7FFFu + ((u >> 16) & 1u);
    return (unsigned short)(u >> 16);
}
__device__ __forceinline__ float bf2f(unsigned short h) {
    return __uint_as_float(((unsigned int)h) << 16);
}

// 8 f32 (scaled by s) -> hi bf16x8 + residual-lo bf16x8 (fp32-accurate split)
__device__ __forceinline__ void cvt8s(const float4 a, const float4 b, float s,
                                      bf16x8* hi, bf16x8* lo) {
    float v[8] = {a.x * s, a.y * s, a.z * s, a.w * s,
                  b.x * s, b.y * s, b.z * s, b.w * s};
#pragma unroll
    for (int e = 0; e < 8; ++e) {
        unsigned short h = f2bf_rne(v[e]);
        (*hi)[e] = (short)h;
        (*lo)[e] = (short)f2bf_rne(v[e] - bf2f(h));
    }
}

// Fused SNN: per block = 16 batch rows x 64 hidden cols, all 512 timesteps.
// mem/cnt live in MFMA C-fragment layout registers for the whole kernel.
// Writes spike counts cnt[B,H] to workspace; epilogue kernel applies W2.
__global__ __launch_bounds__(256, 1) void snn_mfma(
    const float* __restrict__ x,      // [B, T, 128]
    const float* __restrict__ W1,     // [H, 128]
    const float* __restrict__ b1,     // [H]
    float* __restrict__ cnt_ws)       // [B, H]
{
    __shared__ short ldsA[2][2][16 * IN_DIM];   // [buf][hi/lo][m*128 + k], swizzled

    const int bid  = blockIdx.x;
    const int hblk = bid >> 5;        // 0..7  (bid = hblk*32 + bblk -> same-bblk siblings share XCD)
    const int bblk = bid & 31;        // 0..31
    const int b0   = bblk * 16;
    const int tid  = threadIdx.x;
    const int wave = tid >> 6;        // 0..3
    const int lane = tid & 63;
    const int l15  = lane & 15;
    const int lg   = lane >> 4;       // 0..3
    const int hbase = hblk * 64 + wave * 16;

    // ---- B-operand fragments from W1 (held in regs all T steps) ----
    // B[k][n] = W1[hbase+n][k]; lane: n = lane&15, k = lg*8 + kf*32 + e
    bf16x8 whi[4], wlo[4];
    {
        const float* wp = W1 + (size_t)(hbase + l15) * IN_DIM + lg * 8;
#pragma unroll
        for (int kf = 0; kf < 4; ++kf) {
            const float4* p = reinterpret_cast<const float4*>(wp + kf * 32);
            float4 pa = p[0], pb = p[1];
            cvt8s(pa, pb, 1.0f, &whi[kf], &wlo[kf]);
        }
    }
    const float b1h = b1[hbase + l15];

    // ---- staging (write) address: this lane stages row m_w, chunk l15 ----
    const int m_w  = wave * 4 + lg;
    const int widx = m_w * IN_DIM + ((l15 ^ (m_w & 7)) * 8);   // XOR-swizzled chunk
    const float* xrow = x + ((size_t)(b0 + m_w) * TSTEPS) * IN_DIM + l15 * 8;

    // ---- A-frag (read) addresses: row m = lane&15, chunk = lg + 4*kf ----
    int ridx[4];
#pragma unroll
    for (int kf = 0; kf < 4; ++kf)
        ridx[kf] = l15 * IN_DIM + (((lg + 4 * kf) ^ (l15 & 7)) * 8);

    f32x4 mem = {0.f, 0.f, 0.f, 0.f};
    f32x4 cnt = {0.f, 0.f, 0.f, 0.f};

    // ---- prologue: stage t=0, prefetch t=1,t=2 into regs ----
    {
        const float4* p = reinterpret_cast<const float4*>(xrow);
        bf16x8 h8, l8;
        cvt8s(p[0], p[1], 2.0f, &h8, &l8);
        *(bf16x8*)&ldsA[0][0][widx] = h8;
        *(bf16x8*)&ldsA[0][1][widx] = l8;
    }
    float4 rA0, rA1, rB0, rB1;
    {
        const float4* p1 = reinterpret_cast<const float4*>(xrow + 1 * IN_DIM);
        rA0 = p1[0]; rA1 = p1[1];
        const float4* p2 = reinterpret_cast<const float4*>(xrow + 2 * IN_DIM);
        rB0 = p2[0]; rB1 = p2[1];
    }
    __syncthreads();

#define SNN_BODY(T_CUR, RC0, RC1)                                              \
    {                                                                          \
        const int buf = (T_CUR) & 1;                                           \
        /* write tile t+1 (regs loaded 2 bodies ago) into other buffer */      \
        if ((T_CUR) + 1 < TSTEPS) {                                            \
            bf16x8 h8, l8;                                                     \
            cvt8s(RC0, RC1, 2.0f, &h8, &l8);                                   \
            *(bf16x8*)&ldsA[buf ^ 1][0][widx] = h8;                            \
            *(bf16x8*)&ldsA[buf ^ 1][1][widx] = l8;                            \
        }                                                                      \
        /* read A fragments for tile t */                                      \
        bf16x8 ahi[4], alo[4];                                                 \
        _Pragma("unroll")                                                      \
        for (int kf = 0; kf < 4; ++kf) {                                       \
            ahi[kf] = *(const bf16x8*)&ldsA[buf][0][ridx[kf]];                 \
            alo[kf] = *(const bf16x8*)&ldsA[buf][1][ridx[kf]];                 \
        }                                                                      \
        /* issue prefetch of tile t+3 (consumed 2 bodies later) */             \
        {                                                                      \
            int tld = (T_CUR) + 3;                                             \
            if (tld > TSTEPS - 1) tld = TSTEPS - 1;                            \
            const float4* p = reinterpret_cast<const float4*>(                 \
                xrow + (size_t)tld * IN_DIM);                                  \
            RC0 = p[0]; RC1 = p[1];                                            \
        }                                                                      \
        /* 3 independent MFMA chains: hi*hi (+b1), hi*lo, lo*hi */             \
        f32x4 chh = {b1h, b1h, b1h, b1h};                                      \
        f32x4 chl = {0.f, 0.f, 0.f, 0.f};                                      \
        f32x4 clh = {0.f, 0.f, 0.f, 0.f};                                      \
        _Pragma("unroll")                                                      \
        for (int kf = 0; kf < 4; ++kf) {                                       \
            chh = __builtin_amdgcn_mfma_f32_16x16x32_bf16(ahi[kf], whi[kf], chh, 0, 0, 0); \
            chl = __builtin_amdgcn_mfma_f32_16x16x32_bf16(ahi[kf], wlo[kf], chl, 0, 0, 0); \
            clh = __builtin_amdgcn_mfma_f32_16x16x32_bf16(alo[kf], whi[kf], clh, 0, 0, 0); \
        }                                                                      \
        /* LIF recurrence, snntorch order (reset from previous mem) */         \
        _Pragma("unroll")                                                      \
        for (int r = 0; r < 4; ++r) {                                          \
            float cur = (chh[r] + chl[r]) + clh[r];                            \
            float dec = fmaf(BETA, mem[r], cur);                               \
            mem[r] = (mem[r] > THRESH) ? (dec - THRESH) : dec;                 \
            cnt[r] += (mem[r] > THRESH) ? 1.0f : 0.0f;                         \
        }                                                                      \
        __syncthreads();                                                       \
    }

    for (int t = 0; t < TSTEPS; t += 2) {
        SNN_BODY(t,     rA0, rA1)
        SNN_BODY(t + 1, rB0, rB1)
    }
#undef SNN_BODY

    // ---- store spike counts; C-layout: row m=(lane>>4)*4+r, col n=lane&15 ----
    float* cp = cnt_ws + (size_t)b0 * HIDDEN + hbase + l15;
#pragma unroll
    for (int r = 0; r < 4; ++r)
        cp[(size_t)(lg * 4 + r) * HIDDEN] = cnt[r];
}

// out[b,c] = (sum_h cnt[b,h] * W2[c,h]) / T + b2[c]
__global__ __launch_bounds__(64, 1) void snn_out(
    const float* __restrict__ cnt_ws, const float* __restrict__ W2,
    const float* __restrict__ b2, float* __restrict__ out)
{
    const int b = blockIdx.x;
    const int lane = threadIdx.x;
    float c8[8];
#pragma unroll
    for (int j = 0; j < 8; ++j)
        c8[j] = cnt_ws[(size_t)b * HIDDEN + lane + 64 * j];
#pragma unroll
    for (int c = 0; c < NCLASS; ++c) {
        float s = 0.f;
#pragma unroll
        for (int j = 0; j < 8; ++j)
            s = fmaf(c8[j], W2[c * HIDDEN + lane + 64 * j], s);
#pragma unroll
        for (int off = 32; off >= 1; off >>= 1)
            s += __shfl_xor(s, off, 64);
        if (lane == c)
            out[(size_t)b * NCLASS + c] = s * (1.0f / (float)TSTEPS) + b2[c];
    }
}

extern "C" void kernel_launch(void* const* d_in, const int* in_sizes, int n_in,
                              void* d_out, int out_size, void* d_ws, size_t ws_size,
                              hipStream_t stream) {
    const float* x  = (const float*)d_in[0];
    const float* W1 = (const float*)d_in[1];
    const float* b1 = (const float*)d_in[2];
    const float* W2 = (const float*)d_in[3];
    const float* b2 = (const float*)d_in[4];
    float* out = (float*)d_out;
    float* cnt_ws = (float*)d_ws;   // [B, H] fp32 = 1 MB

    snn_mfma<<<dim3(32 * 8), dim3(256), 0, stream>>>(x, W1, b1, cnt_ws);
    snn_out<<<dim3(BATCH), dim3(64), 0, stream>>>(cnt_ws, W2, b2, out);
}